// Round 12
// baseline (1039.356 us; speedup 1.0000x reference)
//
#include <hip/hip_runtime.h>
#include <cstdint>
#include <cstddef>

typedef unsigned short u16;
typedef __attribute__((ext_vector_type(4))) float f32x4;
typedef __attribute__((ext_vector_type(8))) short s16x8;

#define BB 8
#define SS 2048
#define DD 1024
#define FF 3072
#define MM (BB*SS)      // 16384 tokens
#define NCH 64          // scan chunks
#define LCH (SS/NCH)    // 32 steps per chunk

__device__ __forceinline__ float bf2f(u16 u){ union{uint32_t i;float f;}v; v.i=((uint32_t)u)<<16; return v.f; }
__device__ __forceinline__ u16 f2bf(float f){ union{float f;uint32_t i;}v; v.f=f; uint32_t r=v.i+0x7FFFu+((v.i>>16)&1u); return (u16)(r>>16); }
__device__ __forceinline__ float sigm(float x){ return 1.f/(1.f+__expf(-x)); }
__device__ __forceinline__ float tanh_f(float x){ return 2.f*sigm(2.f*x)-1.f; }

// ---------------- merged weight conversion ----------------
__global__ void conv_all(const float* __restrict__ Wg, const float* __restrict__ Wv,
                         const float* __restrict__ Wd, const float* __restrict__ Wgate,
                         const float* __restrict__ Wup, const float* __restrict__ Wout,
                         const float* __restrict__ rfw,
                         u16* __restrict__ oGvd, u16* __restrict__ oGu, u16* __restrict__ oWo){
  const int blk = blockIdx.x;
  if (blk < 3072) {
    size_t i = ((size_t)blk*256 + threadIdx.x)*4;
    int row = (int)(i >> 10); int col = (int)(i & 1023);
    const float* src; int srow;
    if (row < 2048) { int grp = row >> 5, w = row & 31; src = (w < 16) ? Wg : Wv; srow = grp*16 + (w & 15); }
    else            { src = Wd; srow = row - 2048; }
    float4 v = *(const float4*)(src + (size_t)srow*1024 + col);
    ushort4 o; o.x=f2bf(v.x); o.y=f2bf(v.y); o.z=f2bf(v.z); o.w=f2bf(v.w);
    *(ushort4*)(oGvd + i) = o;
  } else if (blk < 9216) {
    size_t i = ((size_t)(blk-3072)*256 + threadIdx.x)*4;
    int row = (int)(i >> 10); int col = (int)(i & 1023);
    int group = row >> 5, w = row & 31;
    const float* src = (w < 16) ? Wgate : Wup;
    int srow = group*16 + (w & 15);
    float4 v = *(const float4*)(src + (size_t)srow*1024 + col);
    float4 s = *(const float4*)(rfw + col);
    ushort4 o; o.x=f2bf(v.x*s.x); o.y=f2bf(v.y*s.y); o.z=f2bf(v.z*s.z); o.w=f2bf(v.w*s.w);
    *(ushort4*)(oGu + i) = o;
  } else {
    size_t i = ((size_t)(blk-9216)*256 + threadIdx.x)*4;
    float4 v = *(const float4*)(Wout + i);
    ushort4 o; o.x=f2bf(v.x); o.y=f2bf(v.y); o.z=f2bf(v.z); o.w=f2bf(v.w);
    *(ushort4*)(oWo + i) = o;
  }
}

// ---------------- RMSNorm (mixer): f32 [M,1024] -> bf16 [M,1024] ----------------
__global__ void rmsnorm_k(const float* __restrict__ x, const float* __restrict__ wgt,
                          u16* __restrict__ out){
  const int row = blockIdx.x, t = threadIdx.x;
  float4 v = ((const float4*)(x + (size_t)row*DD))[t];
  float ss = v.x*v.x + v.y*v.y + v.z*v.z + v.w*v.w;
  #pragma unroll
  for (int o = 32; o > 0; o >>= 1) ss += __shfl_down(ss, o, 64);
  __shared__ float sacc[4];
  if ((t & 63) == 0) sacc[t >> 6] = ss;
  __syncthreads();
  float tot = sacc[0] + sacc[1] + sacc[2] + sacc[3];
  float r = rsqrtf(tot * (1.f/(float)DD) + 1e-6f);
  float4 wv = ((const float4*)wgt)[t];
  ushort4 o; o.x=f2bf(v.x*r*wv.x); o.y=f2bf(v.y*r*wv.y); o.z=f2bf(v.z*r*wv.z); o.w=f2bf(v.w*r*wv.w);
  ((ushort4*)(out + (size_t)row*DD))[t] = o;
}

// ---------------- 256x256 8-phase GEMM: C[M,N] = A[M,K]*B[N,K]^T ----------------
// Fragment-register pipelined schedule (R10) with __launch_bounds__(512,2) so the
// allocator has the true budget (1 block/CU, 2 waves/SIMD -> up to 256 VGPR).
// Each phase's frags are read ONE PHASE EARLY, overlapping ds_read with MFMA.
template<int EPI, int NTN>
__global__ __launch_bounds__(512, 2) void gemm256(
    const u16* __restrict__ A, const u16* __restrict__ Bm, int K,
    const float* __restrict__ bg, const float* __restrict__ bv, const float* __restrict__ bd,
    const float* __restrict__ rinv,
    u16* __restrict__ o_xs, u16* __restrict__ o_a,
    u16* __restrict__ o_h, const u16* __restrict__ yres, float* __restrict__ o_out)
{
  __shared__ u16 lds[2*32768];   // [buf][A:16384|B:16384] u16, row-major [256][64] per matrix
  const int tid = threadIdx.x, w = tid >> 6, l = tid & 63;
  const int wr = w >> 2, wc = w & 3;
  // bijective XCD swizzle (gridDim.x % 8 == 0)
  const int nwg = gridDim.x, bid = blockIdx.x;
  const int sw = (bid & 7) * (nwg >> 3) + (bid >> 3);
  const int tm = sw / NTN, tn = sw % NTN;

  // staging: lane covers row w*8+(l>>3), 16B slot (l&7); source slot pre-XORed by row&7
  const int srow  = w*8 + (l >> 3);
  const int sslot = (l & 7) ^ ((l >> 3) & 7);
  const u16* gA = A  + (size_t)(tm*256 + srow)*K + sslot*8;
  const u16* gB = Bm + (size_t)(tn*256 + srow)*K + sslot*8;

#define STAGE_HALF(dbuf, isB, h, tile) do { \
    const u16* gsrc_ = ((isB) ? gB : gA) + ((size_t)(h)*128)*K + (size_t)(tile)*64; \
    u16* ldst_ = &lds[(dbuf)*32768 + (isB)*16384 + (h)*8192 + w*512]; \
    __builtin_amdgcn_global_load_lds((const __attribute__((address_space(1))) void*)gsrc_, \
        (__attribute__((address_space(3))) void*)ldst_, 16, 0, 0); \
    __builtin_amdgcn_global_load_lds((const __attribute__((address_space(1))) void*)(gsrc_ + (size_t)64*K), \
        (__attribute__((address_space(3))) void*)(ldst_ + 4096), 16, 0, 0); \
  } while(0)

  // LDS read addressing (u16 units): row*64 + swizzled_slot*8
  const int aRow = wr*128 + (l & 15);           // + mi*16   (row&7 == l&7)
  const int bRow = wc*64  + (l & 15);           // + ni*16
  const int sl0  = (((l >> 4) ^ (l & 7))) * 8;  // ks=0; ks=1 -> ^32

#define LDA(cb, mi, ks) (*(const s16x8*)&lds[(cb)*32768 + (aRow + (mi)*16)*64 + (sl0 ^ ((ks)*32))])
#define LDB(cb, ni, ks) (*(const s16x8*)&lds[(cb)*32768 + 16384 + (bRow + (ni)*16)*64 + (sl0 ^ ((ks)*32))])

// load 4 A-frags (mi0, mi0+1 x ks0,1) into named bank regs
#define LDA4(P, cb, mi0) do { \
    P##0 = LDA(cb, (mi0),   0); P##1 = LDA(cb, (mi0),   1); \
    P##2 = LDA(cb, (mi0)+1, 0); P##3 = LDA(cb, (mi0)+1, 1); \
  } while(0)

// load 8 B-frags (4 ni x 2 ks) into named bank regs
#define LDB8(P, cb) do { \
    P##_00=LDB(cb,0,0); P##_01=LDB(cb,0,1); \
    P##_10=LDB(cb,1,0); P##_11=LDB(cb,1,1); \
    P##_20=LDB(cb,2,0); P##_21=LDB(cb,2,1); \
    P##_30=LDB(cb,3,0); P##_31=LDB(cb,3,1); \
  } while(0)

#define VMW4 asm volatile("s_waitcnt vmcnt(4)" ::: "memory")

// phase: {stage; [vmcnt]; BAR; preload next frags; MFMA on current frags}
#define PH(STG, VMW, MI0, A0,A1,A2,A3, B00,B01,B10,B11,B20,B21,B30,B31, ...) do { \
    STG; VMW; \
    __builtin_amdgcn_s_barrier(); \
    __VA_ARGS__; \
    __builtin_amdgcn_s_setprio(1); \
    acc[(MI0)  ][0] = __builtin_amdgcn_mfma_f32_16x16x32_bf16(A0, B00, acc[(MI0)  ][0],0,0,0); \
    acc[(MI0)  ][1] = __builtin_amdgcn_mfma_f32_16x16x32_bf16(A0, B10, acc[(MI0)  ][1],0,0,0); \
    acc[(MI0)  ][2] = __builtin_amdgcn_mfma_f32_16x16x32_bf16(A0, B20, acc[(MI0)  ][2],0,0,0); \
    acc[(MI0)  ][3] = __builtin_amdgcn_mfma_f32_16x16x32_bf16(A0, B30, acc[(MI0)  ][3],0,0,0); \
    acc[(MI0)+1][0] = __builtin_amdgcn_mfma_f32_16x16x32_bf16(A2, B00, acc[(MI0)+1][0],0,0,0); \
    acc[(MI0)+1][1] = __builtin_amdgcn_mfma_f32_16x16x32_bf16(A2, B10, acc[(MI0)+1][1],0,0,0); \
    acc[(MI0)+1][2] = __builtin_amdgcn_mfma_f32_16x16x32_bf16(A2, B20, acc[(MI0)+1][2],0,0,0); \
    acc[(MI0)+1][3] = __builtin_amdgcn_mfma_f32_16x16x32_bf16(A2, B30, acc[(MI0)+1][3],0,0,0); \
    acc[(MI0)  ][0] = __builtin_amdgcn_mfma_f32_16x16x32_bf16(A1, B01, acc[(MI0)  ][0],0,0,0); \
    acc[(MI0)  ][1] = __builtin_amdgcn_mfma_f32_16x16x32_bf16(A1, B11, acc[(MI0)  ][1],0,0,0); \
    acc[(MI0)  ][2] = __builtin_amdgcn_mfma_f32_16x16x32_bf16(A1, B21, acc[(MI0)  ][2],0,0,0); \
    acc[(MI0)  ][3] = __builtin_amdgcn_mfma_f32_16x16x32_bf16(A1, B31, acc[(MI0)  ][3],0,0,0); \
    acc[(MI0)+1][0] = __builtin_amdgcn_mfma_f32_16x16x32_bf16(A3, B01, acc[(MI0)+1][0],0,0,0); \
    acc[(MI0)+1][1] = __builtin_amdgcn_mfma_f32_16x16x32_bf16(A3, B11, acc[(MI0)+1][1],0,0,0); \
    acc[(MI0)+1][2] = __builtin_amdgcn_mfma_f32_16x16x32_bf16(A3, B21, acc[(MI0)+1][2],0,0,0); \
    acc[(MI0)+1][3] = __builtin_amdgcn_mfma_f32_16x16x32_bf16(A3, B31, acc[(MI0)+1][3],0,0,0); \
    __builtin_amdgcn_s_setprio(0); \
  } while(0)

  f32x4 acc[8][4] = {};
  s16x8 aX0,aX1,aX2,aX3, aY0,aY1,aY2,aY3;
  s16x8 b0_00,b0_01,b0_10,b0_11,b0_20,b0_21,b0_30,b0_31;
  s16x8 b1_00,b1_01,b1_10,b1_11,b1_20,b1_21,b1_30,b1_31;
  const int nk = K >> 6;   // K/64, even (16 or 48)

  // prologue: tile0 fully into buf0, B of tile1 into buf1 (12 loads)
  STAGE_HALF(0,0,0,0); STAGE_HALF(0,0,1,0);
  STAGE_HALF(0,1,0,0); STAGE_HALF(0,1,1,0);
  STAGE_HALF(1,1,0,1); STAGE_HALF(1,1,1,1);
  asm volatile("s_waitcnt vmcnt(4)" ::: "memory");   // tile0 landed (B(1) may be in flight)
  __builtin_amdgcn_s_barrier();
  LDB8(b0, 0);
  LDA4(aX, 0, 0);

  for (int it = 0, t = 0; it < (nk >> 1); ++it, t += 2) {
    const int tp1 = t + 1;
    int tp2 = t + 2; if (tp2 >= nk) tp2 -= nk;   // wrapped redundant stage on last iter
    int tp3 = t + 3; if (tp3 >= nk) tp3 -= nk;
    PH(STAGE_HALF(1,0,0,tp1),     , 0, aX0,aX1,aX2,aX3, b0_00,b0_01,b0_10,b0_11,b0_20,b0_21,b0_30,b0_31,
       LDA4(aY,0,2));
    PH(STAGE_HALF(1,0,1,tp1),     , 2, aY0,aY1,aY2,aY3, b0_00,b0_01,b0_10,b0_11,b0_20,b0_21,b0_30,b0_31,
       LDA4(aX,0,4));
    PH(STAGE_HALF(0,1,0,tp2),     , 4, aX0,aX1,aX2,aX3, b0_00,b0_01,b0_10,b0_11,b0_20,b0_21,b0_30,b0_31,
       LDA4(aY,0,6));
    PH(STAGE_HALF(0,1,1,tp2), VMW4, 6, aY0,aY1,aY2,aY3, b0_00,b0_01,b0_10,b0_11,b0_20,b0_21,b0_30,b0_31,
       LDA4(aX,1,0); LDB8(b1,1));
    PH(STAGE_HALF(0,0,0,tp2),     , 0, aX0,aX1,aX2,aX3, b1_00,b1_01,b1_10,b1_11,b1_20,b1_21,b1_30,b1_31,
       LDA4(aY,1,2));
    PH(STAGE_HALF(0,0,1,tp2),     , 2, aY0,aY1,aY2,aY3, b1_00,b1_01,b1_10,b1_11,b1_20,b1_21,b1_30,b1_31,
       LDA4(aX,1,4));
    PH(STAGE_HALF(1,1,0,tp3),     , 4, aX0,aX1,aX2,aX3, b1_00,b1_01,b1_10,b1_11,b1_20,b1_21,b1_30,b1_31,
       LDA4(aY,1,6));
    PH(STAGE_HALF(1,1,1,tp3), VMW4, 6, aY0,aY1,aY2,aY3, b1_00,b1_01,b1_10,b1_11,b1_20,b1_21,b1_30,b1_31,
       LDA4(aX,0,0); LDB8(b0,0));
  }
#undef PH
#undef VMW4
#undef LDA4
#undef LDB8
#undef LDA
#undef LDB
#undef STAGE_HALF

  // epilogue: C/D layout col = l&15, row = (l>>4)*4 + i
  const int rb = tm*256 + wr*128 + ((l >> 4) << 2);
  const int lc = l & 15;
  if constexpr (EPI == 0) {
    if (tn < 8) {
      #pragma unroll
      for (int mi = 0; mi < 8; ++mi)
        #pragma unroll
        for (int j = 0; j < 2; ++j) {
          int f = tn*128 + wc*32 + j*16 + lc;
          float bgf = bg[f], bvf = bv[f];
          #pragma unroll
          for (int i = 0; i < 4; ++i) {
            int r = rb + mi*16 + i;
            float g2 = acc[mi][2*j][i]   + bgf;
            float v2 = acc[mi][2*j+1][i] + bvf;
            o_xs[(size_t)r*DD + f] = f2bf(sigm(g2) * tanh_f(v2));
          }
        }
    } else {
      #pragma unroll
      for (int mi = 0; mi < 8; ++mi)
        #pragma unroll
        for (int ni = 0; ni < 4; ++ni) {
          int c = (tn-8)*256 + wc*64 + ni*16 + lc;
          float bdc = bd[c];
          #pragma unroll
          for (int i = 0; i < 4; ++i) {
            int r = rb + mi*16 + i;
            o_a[(size_t)r*DD + c] = f2bf(0.001f + 0.998f*sigm(acc[mi][ni][i] + bdc));
          }
        }
    }
  } else if constexpr (EPI == 1) {
    #pragma unroll
    for (int mi = 0; mi < 8; ++mi) {
      float4 rv = *(const float4*)&rinv[rb + mi*16];
      #pragma unroll
      for (int j = 0; j < 2; ++j) {
        int f = tn*128 + wc*32 + j*16 + lc;
        #pragma unroll
        for (int i = 0; i < 4; ++i) {
          int r = rb + mi*16 + i;
          float rvi = (i==0) ? rv.x : (i==1) ? rv.y : (i==2) ? rv.z : rv.w;
          float g2 = acc[mi][2*j][i]*rvi, u2 = acc[mi][2*j+1][i]*rvi;
          o_h[(size_t)r*FF + f] = f2bf(g2 * sigm(g2) * u2);
        }
      }
    }
  } else {
    #pragma unroll
    for (int mi = 0; mi < 8; ++mi)
      #pragma unroll
      for (int ni = 0; ni < 4; ++ni) {
        int c = tn*256 + wc*64 + ni*16 + lc;
        #pragma unroll
        for (int i = 0; i < 4; ++i) {
          int r = rb + mi*16 + i;
          size_t idx = (size_t)r*DD + c;
          o_out[idx] = bf2f(yres[idx]) + acc[mi][ni][i];
        }
      }
  }
}

// ---------------- chunked causal scan (a stored bf16), vectorized 4 d/thread ------
__global__ __launch_bounds__(256) void scan_pass1(
    const u16* __restrict__ xs, const u16* __restrict__ ab,
    float* __restrict__ Ac, float* __restrict__ Xc){
  const int bid = blockIdx.x;          // B*NCH = 512
  const int c = bid & (NCH-1);
  const int b = bid >> 6;
  const int d0 = threadIdx.x * 4;
  size_t base = ((size_t)b*SS + (size_t)c*LCH)*DD + d0;
  float A0=1.f,A1=1.f,A2=1.f,A3=1.f, X0=0.f,X1=0.f,X2=0.f,X3=0.f;
  for (int tt = 0; tt < LCH; ++tt){
    size_t idx = base + (size_t)tt*DD;
    ushort4 xv = *(const ushort4*)(xs + idx);
    ushort4 av = *(const ushort4*)(ab + idx);
    float a0=bf2f(av.x), a1=bf2f(av.y), a2=bf2f(av.z), a3=bf2f(av.w);
    X0 = a0*X0 + bf2f(xv.x); A0 *= a0;
    X1 = a1*X1 + bf2f(xv.y); A1 *= a1;
    X2 = a2*X2 + bf2f(xv.z); A2 *= a2;
    X3 = a3*X3 + bf2f(xv.w); A3 *= a3;
  }
  size_t o = ((size_t)b*NCH + c)*DD + d0;
  float4 Av; Av.x=A0; Av.y=A1; Av.z=A2; Av.w=A3;
  float4 Xv; Xv.x=X0; Xv.y=X1; Xv.z=X2; Xv.w=X3;
  *(float4*)(Ac + o) = Av;
  *(float4*)(Xc + o) = Xv;
}

__global__ void scan_pass2(const float* __restrict__ Ac, const float* __restrict__ Xc,
                           float* __restrict__ hin){
  int gid = blockIdx.x*256 + threadIdx.x;   // 8192 = B*D
  int b = gid >> 10, d = gid & 1023;
  float h = 0.f;
  for (int c = 0; c < NCH; ++c){
    size_t o = ((size_t)b*NCH + c)*DD + d;
    hin[o] = h;
    h = Ac[o]*h + Xc[o];
  }
}

// pass3: re-scan with prefix; write y1 bf16 + per-row rinv (FFN rms folded into Wgu).
__global__ __launch_bounds__(256) void scan_pass3_y(
    const u16* __restrict__ xs, const u16* __restrict__ ab,
    const float* __restrict__ hin, const float* __restrict__ x,
    u16* __restrict__ ybf, float* __restrict__ rinv)
{
  const int bid = blockIdx.x;          // B*NCH = 512
  const int c = bid & (NCH-1);
  const int b = bid >> 6;
  const int t = threadIdx.x;
  const int d0 = t * 4;
  float h[4];
  size_t hb = ((size_t)b*NCH + c)*DD + d0;
  float4 hv = *(const float4*)(hin + hb);
  h[0]=hv.x; h[1]=hv.y; h[2]=hv.z; h[3]=hv.w;
  __shared__ float sred[4];
  size_t base = ((size_t)b*SS + (size_t)c*LCH)*DD + d0;
  const int row0 = b*SS + c*LCH;
  for (int tt = 0; tt < LCH; ++tt){
    size_t idx = base + (size_t)tt*DD;
    ushort4 xv = *(const ushort4*)(xs + idx);
    ushort4 av = *(const ushort4*)(ab + idx);
    float4 xr = *(const float4*)(x + idx);
    float yv[4]; float ss = 0.f;
    h[0] = bf2f(av.x)*h[0] + bf2f(xv.x); yv[0] = xr.x + h[0]; ss += yv[0]*yv[0];
    h[1] = bf2f(av.y)*h[1] + bf2f(xv.y); yv[1] = xr.y + h[1]; ss += yv[1]*yv[1];
    h[2] = bf2f(av.z)*h[2] + bf2f(xv.z); yv[2] = xr.z + h[2]; ss += yv[2]*yv[2];
    h[3] = bf2f(av.w)*h[3] + bf2f(xv.w); yv[3] = xr.w + h[3]; ss += yv[3]*yv[3];
    #pragma unroll
    for (int o = 32; o > 0; o >>= 1) ss += __shfl_down(ss, o, 64);
    if ((t & 63) == 0) sred[t >> 6] = ss;
    __syncthreads();
    float tot = sred[0] + sred[1] + sred[2] + sred[3];
    float r = rsqrtf(tot * (1.f/(float)DD) + 1e-6f);
    if (t == 0) rinv[row0 + tt] = r;
    ushort4 ov; ov.x=f2bf(yv[0]); ov.y=f2bf(yv[1]); ov.z=f2bf(yv[2]); ov.w=f2bf(yv[3]);
    *(ushort4*)(ybf + idx) = ov;
    __syncthreads();   // protect sred before next iteration overwrites it
  }
}

// ---------------- launch ----------------
extern "C" void kernel_launch(void* const* d_in, const int* in_sizes, int n_in,
                              void* d_out, int out_size, void* d_ws, size_t ws_size,
                              hipStream_t stream) {
  const float* x     = (const float*)d_in[0];
  const float* rmw   = (const float*)d_in[1];
  const float* rfw   = (const float*)d_in[2];
  const float* Wg    = (const float*)d_in[3];
  const float* bg    = (const float*)d_in[4];
  const float* Wv    = (const float*)d_in[5];
  const float* bv    = (const float*)d_in[6];
  const float* Wd    = (const float*)d_in[7];
  const float* bd    = (const float*)d_in[8];
  const float* Wgate = (const float*)d_in[9];
  const float* Wup   = (const float*)d_in[10];
  const float* Wout  = (const float*)d_in[11];
  float* out = (float*)d_out;

  char* p = (char*)d_ws;
  u16*  xn    = (u16*)p;              p += (size_t)MM*DD*2;        // 33.5MB: mixer xn, later ybf
  u16*  Wgvd  = (u16*)p;              p += (size_t)3072*1024*2;    // 6.3MB
  u16*  Wgu   = (u16*)p;              p += (size_t)6144*1024*2;    // 12.6MB
  u16*  Wo    = (u16*)p;              p += (size_t)1024*3072*2;    // 6.3MB
  char* big   = p;                    p += (size_t)MM*FF*2;        // 100.7MB: xs+ab, later hbuf
  u16*  xs    = (u16*)big;                                         // bf16 [M,1024]
  u16*  ab    = (u16*)(big + (size_t)MM*DD*2);                     // bf16 [M,1024]
  u16*  hbuf  = (u16*)big;            // aliases xs/ab after scan
  float* Ac   = (float*)p;            p += (size_t)BB*NCH*DD*4;    // 2MB
  float* Xc   = (float*)p;            p += (size_t)BB*NCH*DD*4;    // 2MB
  float* hin  = (float*)p;            p += (size_t)BB*NCH*DD*4;    // 2MB
  float* rinv = (float*)p;            p += (size_t)MM*4;           // 64KB
  u16*  ybf   = xn;                   // reuse (xn dead after EPI0)

  conv_all<<<12288, 256, 0, stream>>>(Wg, Wv, Wd, Wgate, Wup, Wout, rfw, Wgvd, Wgu, Wo);

  // mixer
  rmsnorm_k<<<MM, 256, 0, stream>>>(x, rmw, xn);
  gemm256<0,12><<<64*12, 512, 0, stream>>>(xn, Wgvd, 1024,
      bg, bv, bd, nullptr, xs, ab, nullptr, nullptr, nullptr);
  scan_pass1<<<BB*NCH, 256, 0, stream>>>(xs, ab, Ac, Xc);
  scan_pass2<<<32, 256, 0, stream>>>(Ac, Xc, hin);
  scan_pass3_y<<<BB*NCH, 256, 0, stream>>>(xs, ab, hin, x, ybf, rinv);

  // FFN (rms weight folded into Wgu; rinv applied in EPI1 epilogue)
  gemm256<1,24><<<64*24, 512, 0, stream>>>(ybf, Wgu, 1024,
      nullptr, nullptr, nullptr, rinv, nullptr, nullptr, hbuf, nullptr, nullptr);
  gemm256<2,4><<<64*4, 512, 0, stream>>>(hbuf, Wo, 3072,
      nullptr, nullptr, nullptr, nullptr, nullptr, nullptr, nullptr, ybf, out);
}

// Round 13
// 489.047 us; speedup vs baseline: 2.1253x; 2.1253x over previous
//
#include <hip/hip_runtime.h>
#include <cstdint>
#include <cstddef>

typedef unsigned short u16;
typedef __attribute__((ext_vector_type(4))) float f32x4;
typedef __attribute__((ext_vector_type(8))) short s16x8;

#define BB 8
#define SS 2048
#define DD 1024
#define FF 3072
#define MM (BB*SS)      // 16384 tokens
#define NCH 64          // scan chunks
#define LCH (SS/NCH)    // 32 steps per chunk

__device__ __forceinline__ float bf2f(u16 u){ union{uint32_t i;float f;}v; v.i=((uint32_t)u)<<16; return v.f; }
__device__ __forceinline__ u16 f2bf(float f){ union{float f;uint32_t i;}v; v.f=f; uint32_t r=v.i+0x7FFFu+((v.i>>16)&1u); return (u16)(r>>16); }
__device__ __forceinline__ float sigm(float x){ return 1.f/(1.f+__expf(-x)); }
__device__ __forceinline__ float tanh_f(float x){ return 2.f*sigm(2.f*x)-1.f; }

// ---------------- merged weight conversion ----------------
__global__ void conv_all(const float* __restrict__ Wg, const float* __restrict__ Wv,
                         const float* __restrict__ Wd, const float* __restrict__ Wgate,
                         const float* __restrict__ Wup, const float* __restrict__ Wout,
                         const float* __restrict__ rfw,
                         u16* __restrict__ oGvd, u16* __restrict__ oGu, u16* __restrict__ oWo){
  const int blk = blockIdx.x;
  if (blk < 3072) {
    size_t i = ((size_t)blk*256 + threadIdx.x)*4;
    int row = (int)(i >> 10); int col = (int)(i & 1023);
    const float* src; int srow;
    if (row < 2048) { int grp = row >> 5, w = row & 31; src = (w < 16) ? Wg : Wv; srow = grp*16 + (w & 15); }
    else            { src = Wd; srow = row - 2048; }
    float4 v = *(const float4*)(src + (size_t)srow*1024 + col);
    ushort4 o; o.x=f2bf(v.x); o.y=f2bf(v.y); o.z=f2bf(v.z); o.w=f2bf(v.w);
    *(ushort4*)(oGvd + i) = o;
  } else if (blk < 9216) {
    size_t i = ((size_t)(blk-3072)*256 + threadIdx.x)*4;
    int row = (int)(i >> 10); int col = (int)(i & 1023);
    int group = row >> 5, w = row & 31;
    const float* src = (w < 16) ? Wgate : Wup;
    int srow = group*16 + (w & 15);
    float4 v = *(const float4*)(src + (size_t)srow*1024 + col);
    float4 s = *(const float4*)(rfw + col);
    ushort4 o; o.x=f2bf(v.x*s.x); o.y=f2bf(v.y*s.y); o.z=f2bf(v.z*s.z); o.w=f2bf(v.w*s.w);
    *(ushort4*)(oGu + i) = o;
  } else {
    size_t i = ((size_t)(blk-9216)*256 + threadIdx.x)*4;
    float4 v = *(const float4*)(Wout + i);
    ushort4 o; o.x=f2bf(v.x); o.y=f2bf(v.y); o.z=f2bf(v.z); o.w=f2bf(v.w);
    *(ushort4*)(oWo + i) = o;
  }
}

// ---------------- RMSNorm (mixer): f32 [M,1024] -> bf16 [M,1024] ----------------
__global__ void rmsnorm_k(const float* __restrict__ x, const float* __restrict__ wgt,
                          u16* __restrict__ out){
  const int row = blockIdx.x, t = threadIdx.x;
  float4 v = ((const float4*)(x + (size_t)row*DD))[t];
  float ss = v.x*v.x + v.y*v.y + v.z*v.z + v.w*v.w;
  #pragma unroll
  for (int o = 32; o > 0; o >>= 1) ss += __shfl_down(ss, o, 64);
  __shared__ float sacc[4];
  if ((t & 63) == 0) sacc[t >> 6] = ss;
  __syncthreads();
  float tot = sacc[0] + sacc[1] + sacc[2] + sacc[3];
  float r = rsqrtf(tot * (1.f/(float)DD) + 1e-6f);
  float4 wv = ((const float4*)wgt)[t];
  ushort4 o; o.x=f2bf(v.x*r*wv.x); o.y=f2bf(v.y*r*wv.y); o.z=f2bf(v.z*r*wv.z); o.w=f2bf(v.w*r*wv.w);
  ((ushort4*)(out + (size_t)row*DD))[t] = o;
}

// ---------------- 256x256 8-phase GEMM: C[M,N] = A[M,K]*B[N,K]^T ----------------
// R11 structure with barrier THINNING: only phases 0,3,4,7 keep {lgkm(0);[vmcnt];BAR}
// (the load-bearing set: P0 protects LOADB(0) reads before P2/P3 B-stages; P3 drains
// A-reads before P4/P5 A-stages + globalizes vmcnt; P4 protects LOADB(1) before
// P6/P7 B-stages; P7 symmetric). P1/P2/P5/P6 run barrier-free: compiler-counted
// waits cover own register deps, and their ds_reads can interleave with MFMA.
template<int EPI, int NTN>
__global__ __launch_bounds__(512) void gemm256(
    const u16* __restrict__ A, const u16* __restrict__ Bm, int K,
    const float* __restrict__ bg, const float* __restrict__ bv, const float* __restrict__ bd,
    const float* __restrict__ rinv,
    u16* __restrict__ o_xs, u16* __restrict__ o_a,
    u16* __restrict__ o_h, const u16* __restrict__ yres, float* __restrict__ o_out)
{
  __shared__ u16 lds[2*32768];   // [buf][A:16384|B:16384] u16, row-major [256][64] per matrix
  const int tid = threadIdx.x, w = tid >> 6, l = tid & 63;
  const int wr = w >> 2, wc = w & 3;
  // bijective XCD swizzle (gridDim.x % 8 == 0)
  const int nwg = gridDim.x, bid = blockIdx.x;
  const int sw = (bid & 7) * (nwg >> 3) + (bid >> 3);
  const int tm = sw / NTN, tn = sw % NTN;

  // staging: lane covers row w*8+(l>>3), 16B slot (l&7); source slot pre-XORed by row&7
  const int srow  = w*8 + (l >> 3);
  const int sslot = (l & 7) ^ ((l >> 3) & 7);
  const u16* gA = A  + (size_t)(tm*256 + srow)*K + sslot*8;
  const u16* gB = Bm + (size_t)(tn*256 + srow)*K + sslot*8;

#define STAGE_HALF(dbuf, isB, h, tile) do { \
    const u16* gsrc_ = ((isB) ? gB : gA) + ((size_t)(h)*128)*K + (size_t)(tile)*64; \
    u16* ldst_ = &lds[(dbuf)*32768 + (isB)*16384 + (h)*8192 + w*512]; \
    __builtin_amdgcn_global_load_lds((const __attribute__((address_space(1))) void*)gsrc_, \
        (__attribute__((address_space(3))) void*)ldst_, 16, 0, 0); \
    __builtin_amdgcn_global_load_lds((const __attribute__((address_space(1))) void*)(gsrc_ + (size_t)64*K), \
        (__attribute__((address_space(3))) void*)(ldst_ + 4096), 16, 0, 0); \
  } while(0)

  // LDS read addressing (u16 units): row*64 + swizzled_slot*8
  const int aRow = wr*128 + (l & 15);           // + mi*16   (row&7 == l&7)
  const int bRow = wc*64  + (l & 15);           // + ni*16
  const int sl0  = (((l >> 4) ^ (l & 7))) * 8;  // ks=0; ks=1 -> ^32

#define LDA(cb, mi, ks) (*(const s16x8*)&lds[(cb)*32768 + (aRow + (mi)*16)*64 + (sl0 ^ ((ks)*32))])
#define LDB(cb, ni, ks) (*(const s16x8*)&lds[(cb)*32768 + 16384 + (bRow + (ni)*16)*64 + (sl0 ^ ((ks)*32))])

#define LOADB(cb) do { \
    bfr[0][0]=LDB(cb,0,0); bfr[0][1]=LDB(cb,0,1); \
    bfr[1][0]=LDB(cb,1,0); bfr[1][1]=LDB(cb,1,1); \
    bfr[2][0]=LDB(cb,2,0); bfr[2][1]=LDB(cb,2,1); \
    bfr[3][0]=LDB(cb,3,0); bfr[3][1]=LDB(cb,3,1); \
  } while(0)

#define MFMA16(cb, mi0, a00,a01,a10,a11) do { \
    __builtin_amdgcn_s_setprio(1); \
    acc[(mi0)  ][0] = __builtin_amdgcn_mfma_f32_16x16x32_bf16(a00, bfr[0][0], acc[(mi0)  ][0],0,0,0); \
    acc[(mi0)  ][1] = __builtin_amdgcn_mfma_f32_16x16x32_bf16(a00, bfr[1][0], acc[(mi0)  ][1],0,0,0); \
    acc[(mi0)  ][2] = __builtin_amdgcn_mfma_f32_16x16x32_bf16(a00, bfr[2][0], acc[(mi0)  ][2],0,0,0); \
    acc[(mi0)  ][3] = __builtin_amdgcn_mfma_f32_16x16x32_bf16(a00, bfr[3][0], acc[(mi0)  ][3],0,0,0); \
    acc[(mi0)+1][0] = __builtin_amdgcn_mfma_f32_16x16x32_bf16(a10, bfr[0][0], acc[(mi0)+1][0],0,0,0); \
    acc[(mi0)+1][1] = __builtin_amdgcn_mfma_f32_16x16x32_bf16(a10, bfr[1][0], acc[(mi0)+1][1],0,0,0); \
    acc[(mi0)+1][2] = __builtin_amdgcn_mfma_f32_16x16x32_bf16(a10, bfr[2][0], acc[(mi0)+1][2],0,0,0); \
    acc[(mi0)+1][3] = __builtin_amdgcn_mfma_f32_16x16x32_bf16(a10, bfr[3][0], acc[(mi0)+1][3],0,0,0); \
    acc[(mi0)  ][0] = __builtin_amdgcn_mfma_f32_16x16x32_bf16(a01, bfr[0][1], acc[(mi0)  ][0],0,0,0); \
    acc[(mi0)  ][1] = __builtin_amdgcn_mfma_f32_16x16x32_bf16(a01, bfr[1][1], acc[(mi0)  ][1],0,0,0); \
    acc[(mi0)  ][2] = __builtin_amdgcn_mfma_f32_16x16x32_bf16(a01, bfr[2][1], acc[(mi0)  ][2],0,0,0); \
    acc[(mi0)  ][3] = __builtin_amdgcn_mfma_f32_16x16x32_bf16(a01, bfr[3][1], acc[(mi0)  ][3],0,0,0); \
    acc[(mi0)+1][0] = __builtin_amdgcn_mfma_f32_16x16x32_bf16(a11, bfr[0][1], acc[(mi0)+1][0],0,0,0); \
    acc[(mi0)+1][1] = __builtin_amdgcn_mfma_f32_16x16x32_bf16(a11, bfr[1][1], acc[(mi0)+1][1],0,0,0); \
    acc[(mi0)+1][2] = __builtin_amdgcn_mfma_f32_16x16x32_bf16(a11, bfr[2][1], acc[(mi0)+1][2],0,0,0); \
    acc[(mi0)+1][3] = __builtin_amdgcn_mfma_f32_16x16x32_bf16(a11, bfr[3][1], acc[(mi0)+1][3],0,0,0); \
    __builtin_amdgcn_s_setprio(0); \
  } while(0)

// barriered phase: {reads; stage; lgkm(0); [vmcnt]; BAR; MFMA}
#define PHASE_B(cb, mi0, STAGE_STMT, ...) do { \
    s16x8 a00 = LDA(cb, (mi0),   0), a01 = LDA(cb, (mi0),   1); \
    s16x8 a10 = LDA(cb, (mi0)+1, 0), a11 = LDA(cb, (mi0)+1, 1); \
    STAGE_STMT; \
    asm volatile("s_waitcnt lgkmcnt(0)" ::: "memory"); \
    __VA_ARGS__; \
    __builtin_amdgcn_s_barrier(); \
    MFMA16(cb, mi0, a00,a01,a10,a11); \
  } while(0)

// barrier-free phase: {reads; stage; MFMA} — compiler-counted waits handle deps
#define PHASE_NB(cb, mi0, STAGE_STMT) do { \
    s16x8 a00 = LDA(cb, (mi0),   0), a01 = LDA(cb, (mi0),   1); \
    s16x8 a10 = LDA(cb, (mi0)+1, 0), a11 = LDA(cb, (mi0)+1, 1); \
    STAGE_STMT; \
    MFMA16(cb, mi0, a00,a01,a10,a11); \
  } while(0)

  f32x4 acc[8][4] = {};
  s16x8 bfr[4][2];
  const int nk = K >> 6;   // K/64, even (16 or 48)

  // prologue: tile0 fully into buf0, B of tile1 into buf1 (12 loads)
  STAGE_HALF(0,0,0,0); STAGE_HALF(0,0,1,0);
  STAGE_HALF(0,1,0,0); STAGE_HALF(0,1,1,0);
  STAGE_HALF(1,1,0,1); STAGE_HALF(1,1,1,1);
  asm volatile("s_waitcnt vmcnt(4)" ::: "memory");   // tile0 landed (B(1) may be in flight)
  __builtin_amdgcn_s_barrier();

  for (int it = 0, t = 0; it < (nk >> 1); ++it, t += 2) {
    const int tp1 = t + 1;
    int tp2 = t + 2; if (tp2 >= nk) tp2 -= nk;   // wrapped redundant stage on last iter
    int tp3 = t + 3; if (tp3 >= nk) tp3 -= nk;
    LOADB(0);
    PHASE_B (0, 0, STAGE_HALF(1,0,0,tp1), );
    PHASE_NB(0, 2, STAGE_HALF(1,0,1,tp1));
    PHASE_NB(0, 4, STAGE_HALF(0,1,0,tp2));
    PHASE_B (0, 6, STAGE_HALF(0,1,1,tp2), asm volatile("s_waitcnt vmcnt(4)" ::: "memory"));
    LOADB(1);
    PHASE_B (1, 0, STAGE_HALF(0,0,0,tp2), );
    PHASE_NB(1, 2, STAGE_HALF(0,0,1,tp2));
    PHASE_NB(1, 4, STAGE_HALF(1,1,0,tp3));
    PHASE_B (1, 6, STAGE_HALF(1,1,1,tp3), asm volatile("s_waitcnt vmcnt(4)" ::: "memory"));
  }
#undef PHASE_B
#undef PHASE_NB
#undef MFMA16
#undef LOADB
#undef LDA
#undef LDB
#undef STAGE_HALF

  // epilogue: C/D layout col = l&15, row = (l>>4)*4 + i
  const int rb = tm*256 + wr*128 + ((l >> 4) << 2);
  const int lc = l & 15;
  if constexpr (EPI == 0) {
    if (tn < 8) {
      #pragma unroll
      for (int mi = 0; mi < 8; ++mi)
        #pragma unroll
        for (int j = 0; j < 2; ++j) {
          int f = tn*128 + wc*32 + j*16 + lc;
          float bgf = bg[f], bvf = bv[f];
          #pragma unroll
          for (int i = 0; i < 4; ++i) {
            int r = rb + mi*16 + i;
            float g2 = acc[mi][2*j][i]   + bgf;
            float v2 = acc[mi][2*j+1][i] + bvf;
            o_xs[(size_t)r*DD + f] = f2bf(sigm(g2) * tanh_f(v2));
          }
        }
    } else {
      #pragma unroll
      for (int mi = 0; mi < 8; ++mi)
        #pragma unroll
        for (int ni = 0; ni < 4; ++ni) {
          int c = (tn-8)*256 + wc*64 + ni*16 + lc;
          float bdc = bd[c];
          #pragma unroll
          for (int i = 0; i < 4; ++i) {
            int r = rb + mi*16 + i;
            o_a[(size_t)r*DD + c] = f2bf(0.001f + 0.998f*sigm(acc[mi][ni][i] + bdc));
          }
        }
    }
  } else if constexpr (EPI == 1) {
    #pragma unroll
    for (int mi = 0; mi < 8; ++mi) {
      float4 rv = *(const float4*)&rinv[rb + mi*16];
      #pragma unroll
      for (int j = 0; j < 2; ++j) {
        int f = tn*128 + wc*32 + j*16 + lc;
        #pragma unroll
        for (int i = 0; i < 4; ++i) {
          int r = rb + mi*16 + i;
          float rvi = (i==0) ? rv.x : (i==1) ? rv.y : (i==2) ? rv.z : rv.w;
          float g2 = acc[mi][2*j][i]*rvi, u2 = acc[mi][2*j+1][i]*rvi;
          o_h[(size_t)r*FF + f] = f2bf(g2 * sigm(g2) * u2);
        }
      }
    }
  } else {
    #pragma unroll
    for (int mi = 0; mi < 8; ++mi)
      #pragma unroll
      for (int ni = 0; ni < 4; ++ni) {
        int c = tn*256 + wc*64 + ni*16 + lc;
        #pragma unroll
        for (int i = 0; i < 4; ++i) {
          int r = rb + mi*16 + i;
          size_t idx = (size_t)r*DD + c;
          o_out[idx] = bf2f(yres[idx]) + acc[mi][ni][i];
        }
      }
  }
}

// ---------------- chunked causal scan (a stored bf16), vectorized 4 d/thread ------
__global__ __launch_bounds__(256) void scan_pass1(
    const u16* __restrict__ xs, const u16* __restrict__ ab,
    float* __restrict__ Ac, float* __restrict__ Xc){
  const int bid = blockIdx.x;          // B*NCH = 512
  const int c = bid & (NCH-1);
  const int b = bid >> 6;
  const int d0 = threadIdx.x * 4;
  size_t base = ((size_t)b*SS + (size_t)c*LCH)*DD + d0;
  float A0=1.f,A1=1.f,A2=1.f,A3=1.f, X0=0.f,X1=0.f,X2=0.f,X3=0.f;
  for (int tt = 0; tt < LCH; ++tt){
    size_t idx = base + (size_t)tt*DD;
    ushort4 xv = *(const ushort4*)(xs + idx);
    ushort4 av = *(const ushort4*)(ab + idx);
    float a0=bf2f(av.x), a1=bf2f(av.y), a2=bf2f(av.z), a3=bf2f(av.w);
    X0 = a0*X0 + bf2f(xv.x); A0 *= a0;
    X1 = a1*X1 + bf2f(xv.y); A1 *= a1;
    X2 = a2*X2 + bf2f(xv.z); A2 *= a2;
    X3 = a3*X3 + bf2f(xv.w); A3 *= a3;
  }
  size_t o = ((size_t)b*NCH + c)*DD + d0;
  float4 Av; Av.x=A0; Av.y=A1; Av.z=A2; Av.w=A3;
  float4 Xv; Xv.x=X0; Xv.y=X1; Xv.z=X2; Xv.w=X3;
  *(float4*)(Ac + o) = Av;
  *(float4*)(Xc + o) = Xv;
}

__global__ void scan_pass2(const float* __restrict__ Ac, const float* __restrict__ Xc,
                           float* __restrict__ hin){
  int gid = blockIdx.x*256 + threadIdx.x;   // 8192 = B*D
  int b = gid >> 10, d = gid & 1023;
  float h = 0.f;
  for (int c = 0; c < NCH; ++c){
    size_t o = ((size_t)b*NCH + c)*DD + d;
    hin[o] = h;
    h = Ac[o]*h + Xc[o];
  }
}

// pass3: re-scan with prefix; write y1 bf16 + per-row rinv (FFN rms folded into Wgu).
__global__ __launch_bounds__(256) void scan_pass3_y(
    const u16* __restrict__ xs, const u16* __restrict__ ab,
    const float* __restrict__ hin, const float* __restrict__ x,
    u16* __restrict__ ybf, float* __restrict__ rinv)
{
  const int bid = blockIdx.x;          // B*NCH = 512
  const int c = bid & (NCH-1);
  const int b = bid >> 6;
  const int t = threadIdx.x;
  const int d0 = t * 4;
  float h[4];
  size_t hb = ((size_t)b*NCH + c)*DD + d0;
  float4 hv = *(const float4*)(hin + hb);
  h[0]=hv.x; h[1]=hv.y; h[2]=hv.z; h[3]=hv.w;
  __shared__ float sred[4];
  size_t base = ((size_t)b*SS + (size_t)c*LCH)*DD + d0;
  const int row0 = b*SS + c*LCH;
  for (int tt = 0; tt < LCH; ++tt){
    size_t idx = base + (size_t)tt*DD;
    ushort4 xv = *(const ushort4*)(xs + idx);
    ushort4 av = *(const ushort4*)(ab + idx);
    float4 xr = *(const float4*)(x + idx);
    float yv[4]; float ss = 0.f;
    h[0] = bf2f(av.x)*h[0] + bf2f(xv.x); yv[0] = xr.x + h[0]; ss += yv[0]*yv[0];
    h[1] = bf2f(av.y)*h[1] + bf2f(xv.y); yv[1] = xr.y + h[1]; ss += yv[1]*yv[1];
    h[2] = bf2f(av.z)*h[2] + bf2f(xv.z); yv[2] = xr.z + h[2]; ss += yv[2]*yv[2];
    h[3] = bf2f(av.w)*h[3] + bf2f(xv.w); yv[3] = xr.w + h[3]; ss += yv[3]*yv[3];
    #pragma unroll
    for (int o = 32; o > 0; o >>= 1) ss += __shfl_down(ss, o, 64);
    if ((t & 63) == 0) sred[t >> 6] = ss;
    __syncthreads();
    float tot = sred[0] + sred[1] + sred[2] + sred[3];
    float r = rsqrtf(tot * (1.f/(float)DD) + 1e-6f);
    if (t == 0) rinv[row0 + tt] = r;
    ushort4 ov; ov.x=f2bf(yv[0]); ov.y=f2bf(yv[1]); ov.z=f2bf(yv[2]); ov.w=f2bf(yv[3]);
    *(ushort4*)(ybf + idx) = ov;
    __syncthreads();   // protect sred before next iteration overwrites it
  }
}

// ---------------- launch ----------------
extern "C" void kernel_launch(void* const* d_in, const int* in_sizes, int n_in,
                              void* d_out, int out_size, void* d_ws, size_t ws_size,
                              hipStream_t stream) {
  const float* x     = (const float*)d_in[0];
  const float* rmw   = (const float*)d_in[1];
  const float* rfw   = (const float*)d_in[2];
  const float* Wg    = (const float*)d_in[3];
  const float* bg    = (const float*)d_in[4];
  const float* Wv    = (const float*)d_in[5];
  const float* bv    = (const float*)d_in[6];
  const float* Wd    = (const float*)d_in[7];
  const float* bd    = (const float*)d_in[8];
  const float* Wgate = (const float*)d_in[9];
  const float* Wup   = (const float*)d_in[10];
  const float* Wout  = (const float*)d_in[11];
  float* out = (float*)d_out;

  char* p = (char*)d_ws;
  u16*  xn    = (u16*)p;              p += (size_t)MM*DD*2;        // 33.5MB: mixer xn, later ybf
  u16*  Wgvd  = (u16*)p;              p += (size_t)3072*1024*2;    // 6.3MB
  u16*  Wgu   = (u16*)p;              p += (size_t)6144*1024*2;    // 12.6MB
  u16*  Wo    = (u16*)p;              p += (size_t)1024*3072*2;    // 6.3MB
  char* big   = p;                    p += (size_t)MM*FF*2;        // 100.7MB: xs+ab, later hbuf
  u16*  xs    = (u16*)big;                                         // bf16 [M,1024]
  u16*  ab    = (u16*)(big + (size_t)MM*DD*2);                     // bf16 [M,1024]
  u16*  hbuf  = (u16*)big;            // aliases xs/ab after scan
  float* Ac   = (float*)p;            p += (size_t)BB*NCH*DD*4;    // 2MB
  float* Xc   = (float*)p;            p += (size_t)BB*NCH*DD*4;    // 2MB
  float* hin  = (float*)p;            p += (size_t)BB*NCH*DD*4;    // 2MB
  float* rinv = (float*)p;            p += (size_t)MM*4;           // 64KB
  u16*  ybf   = xn;                   // reuse (xn dead after EPI0)

  conv_all<<<12288, 256, 0, stream>>>(Wg, Wv, Wd, Wgate, Wup, Wout, rfw, Wgvd, Wgu, Wo);

  // mixer
  rmsnorm_k<<<MM, 256, 0, stream>>>(x, rmw, xn);
  gemm256<0,12><<<64*12, 512, 0, stream>>>(xn, Wgvd, 1024,
      bg, bv, bd, nullptr, xs, ab, nullptr, nullptr, nullptr);
  scan_pass1<<<BB*NCH, 256, 0, stream>>>(xs, ab, Ac, Xc);
  scan_pass2<<<32, 256, 0, stream>>>(Ac, Xc, hin);
  scan_pass3_y<<<BB*NCH, 256, 0, stream>>>(xs, ab, hin, x, ybf, rinv);

  // FFN (rms weight folded into Wgu; rinv applied in EPI1 epilogue)
  gemm256<1,24><<<64*24, 512, 0, stream>>>(ybf, Wgu, 1024,
      nullptr, nullptr, nullptr, rinv, nullptr, nullptr, hbuf, nullptr, nullptr);
  gemm256<2,4><<<64*4, 512, 0, stream>>>(hbuf, Wo, 3072,
      nullptr, nullptr, nullptr, nullptr, nullptr, nullptr, nullptr, ybf, out);
}